// Round 1
// baseline (3001.282 us; speedup 1.0000x reference)
//
#include <hip/hip_runtime.h>
#include <cstddef>
#include <cstdint>

typedef float f4 __attribute__((ext_vector_type(4)));

#define HID 64

// ---------------- degree / normalization ----------------
__global__ __launch_bounds__(256) void k_init_deg(float* deg, int N) {
    int i = blockIdx.x * 256 + threadIdx.x;
    if (i < N) deg[i] = 1.0f;  // self-loop
}

__global__ __launch_bounds__(256) void k_count(const int* __restrict__ col,
                                               float* __restrict__ deg, int E) {
    int e = blockIdx.x * 256 + threadIdx.x;
    if (e < E) unsafeAtomicAdd(&deg[col[e]], 1.0f);
}

__global__ __launch_bounds__(256) void k_rsqrt(float* deg, int N) {
    int i = blockIdx.x * 256 + threadIdx.x;
    if (i < N) deg[i] = rsqrtf(deg[i]);
}

// ---------------- GEMM: out = (X[N,K] @ W[K,64]) * scale[n] + bias[c] ----------------
// 64-node x 64-col tile per block, 256 threads, each thread 4x4 micro-tile.
// X tile staged transposed in LDS (xs[k][node], stride 68 to keep f4 alignment,
// conflict-free: staging writes vary node across lanes -> banks spread).
// In-place safe (X==out*) because each block stages all its X rows before writing.
template<int K>
__global__ __launch_bounds__(256) void k_gemm(
    const float* __restrict__ X, const float* __restrict__ W,
    const float* __restrict__ bias, const float* __restrict__ scale,
    float* __restrict__ out1, float* __restrict__ out2, int N)
{
    __shared__ float xs[64][68];
    __shared__ float ws[64][64];
    const int t = threadIdx.x;
    const int nbase = blockIdx.x * 64;
    const int c4 = (t & 15) * 4;
    const int n4 = (t >> 4) * 4;

    float acc[4][4] = {{0.f,0.f,0.f,0.f},{0.f,0.f,0.f,0.f},{0.f,0.f,0.f,0.f},{0.f,0.f,0.f,0.f}};

    const int node = t & 63;
    const int gn = nbase + node;
    const f4* Xrow = (gn < N) ? (const f4*)(X + (size_t)gn * K) : nullptr;
    const f4* W4 = (const f4*)W;

    for (int kt = 0; kt < K / 64; ++kt) {
        __syncthreads();
        // stage X (transposed): thread t handles node=t&63, k4r = i*4 + (t>>6)
        #pragma unroll
        for (int i = 0; i < 4; ++i) {
            int k4r = i * 4 + (t >> 6);
            f4 v = {0.f, 0.f, 0.f, 0.f};
            if (Xrow) v = Xrow[kt * 16 + k4r];
            xs[k4r * 4 + 0][node] = v[0];
            xs[k4r * 4 + 1][node] = v[1];
            xs[k4r * 4 + 2][node] = v[2];
            xs[k4r * 4 + 3][node] = v[3];
        }
        // stage W tile [64][64]
        #pragma unroll
        for (int i = 0; i < 4; ++i) {
            int f = i * 256 + t;
            int k = f >> 4, m4 = f & 15;
            *(f4*)&ws[k][m4 * 4] = W4[(size_t)(kt * 64 + k) * 16 + m4];
        }
        __syncthreads();
        #pragma unroll 8
        for (int k = 0; k < 64; ++k) {
            f4 xv = *(const f4*)&xs[k][n4];
            f4 wv = *(const f4*)&ws[k][c4];
            #pragma unroll
            for (int i2 = 0; i2 < 4; ++i2)
                #pragma unroll
                for (int j = 0; j < 4; ++j)
                    acc[i2][j] += xv[i2] * wv[j];
        }
    }

    #pragma unroll
    for (int i = 0; i < 4; ++i) {
        int g = nbase + n4 + i;
        if (g < N) {
            float s = scale ? scale[g] : 1.0f;
            f4 r;
            #pragma unroll
            for (int j = 0; j < 4; ++j) {
                float b = bias ? bias[c4 + j] : 0.0f;
                r[j] = acc[i][j] * s + b;
            }
            *(f4*)(out1 + (size_t)g * HID + c4) = r;
            if (out2) *(f4*)(out2 + (size_t)g * HID + c4) = r;
        }
    }
}

// ---------------- edge scatter: acc[col] += g[row], 16 threads/edge ----------------
__global__ __launch_bounds__(256) void k_scatter(
    const float* __restrict__ g, const int* __restrict__ row, const int* __restrict__ col,
    float* __restrict__ acc, int E)
{
    int t = blockIdx.x * 256 + threadIdx.x;
    int e = t >> 4;
    if (e >= E) return;
    int c4 = (t & 15) * 4;
    int r = row[e], c = col[e];
    f4 v = *(const f4*)(g + (size_t)r * HID + c4);
    float* dst = acc + (size_t)c * HID + c4;
    unsafeAtomicAdd(dst + 0, v[0]);
    unsafeAtomicAdd(dst + 1, v[1]);
    unsafeAtomicAdd(dst + 2, v[2]);
    unsafeAtomicAdd(dst + 3, v[3]);
}

// ---------------- finish: out = acc*dis[node] + bias[c], optional relu (in-place ok) ----------------
__global__ __launch_bounds__(256) void k_finish(
    const float* __restrict__ acc, const float* __restrict__ dis, const float* __restrict__ bias,
    float* __restrict__ out, int N, int do_relu)
{
    int t = blockIdx.x * 256 + threadIdx.x;  // f4 index
    if (t >= N * 16) return;
    int node = t >> 4, c4 = (t & 15) * 4;
    float s = dis[node];
    f4 v = *(const f4*)(acc + (size_t)t * 4);
    f4 r;
    #pragma unroll
    for (int j = 0; j < 4; ++j) {
        r[j] = v[j] * s + bias[c4 + j];
        if (do_relu) r[j] = r[j] > 0.f ? r[j] : 0.f;
    }
    *(f4*)(out + (size_t)t * 4) = r;
}

// ---------------- pair scorer: sigmoid(relu(A[s]+B[d]) . w2 + b2) ----------------
__global__ __launch_bounds__(256) void k_pair(
    const float* __restrict__ A, const float* __restrict__ B,
    const int* __restrict__ pairs, const float* __restrict__ w2, const float* __restrict__ b2,
    float* __restrict__ out, int P)
{
    __shared__ float w2s[64];
    if (threadIdx.x < 64) w2s[threadIdx.x] = w2[threadIdx.x];
    __syncthreads();
    int p = blockIdx.x * 256 + threadIdx.x;
    if (p >= P) return;
    int s = pairs[p], d = pairs[P + p];
    const f4* a4 = (const f4*)(A + (size_t)s * HID);
    const f4* b4 = (const f4*)(B + (size_t)d * HID);
    float acc = b2[0];
    #pragma unroll
    for (int i = 0; i < 16; ++i) {
        f4 av = a4[i], bv = b4[i];
        #pragma unroll
        for (int j = 0; j < 4; ++j) {
            float z = av[j] + bv[j];
            z = z > 0.f ? z : 0.f;
            acc += z * w2s[i * 4 + j];
        }
    }
    out[p] = 1.0f / (1.0f + __expf(-acc));
}

extern "C" void kernel_launch(void* const* d_in, const int* in_sizes, int n_in,
                              void* d_out, int out_size, void* d_ws, size_t ws_size,
                              hipStream_t stream)
{
    if (n_in < 11) return;
    const float* x    = (const float*)d_in[0];
    const int*   ei   = (const int*)d_in[1];
    const int*   ep   = (const int*)d_in[2];
    const float* W1   = (const float*)d_in[3];
    const float* b1   = (const float*)d_in[4];
    const float* W2   = (const float*)d_in[5];
    const float* b2   = (const float*)d_in[6];
    const float* lpW1 = (const float*)d_in[7];
    const float* lpb1 = (const float*)d_in[8];
    const float* lpW2 = (const float*)d_in[9];
    const float* lpb2 = (const float*)d_in[10];
    const int N = in_sizes[0] / 128;
    const int E = in_sizes[1] / 2;
    const int P = in_sizes[2] / 2;

    float* dis  = (float*)d_ws;
    float* bufA = dis + 262144;                 // 1MB reserved for deg/dis
    float* bufB = bufA + (size_t)N * HID;
    size_t need = (262144 + 2 * (size_t)N * HID) * sizeof(float);
    if (ws_size < need) return;
    float* out = (float*)d_out;

    // normalization coefficients
    k_init_deg<<<(N + 255) / 256, 256, 0, stream>>>(dis, N);
    k_count<<<(E + 255) / 256, 256, 0, stream>>>(ei + E, dis, E);
    k_rsqrt<<<(N + 255) / 256, 256, 0, stream>>>(dis, N);

    const int gb = (N + 63) / 64;
    const int sb = (int)(((size_t)E * 16 + 255) / 256);
    const int fb = (N * 16 + 255) / 256;

    // layer 1: g1->bufA, acc1-init->bufB
    k_gemm<128><<<gb, 256, 0, stream>>>(x, W1, nullptr, dis, bufA, bufB, N);
    k_scatter<<<sb, 256, 0, stream>>>(bufA, ei, ei + E, bufB, E);
    k_finish<<<fb, 256, 0, stream>>>(bufB, dis, b1, bufB, N, 1);   // h1 in bufB

    // layer 2: g2->bufA, acc2-init->bufB (in-place safe)
    k_gemm<64><<<gb, 256, 0, stream>>>(bufB, W2, nullptr, dis, bufA, bufB, N);
    k_scatter<<<sb, 256, 0, stream>>>(bufA, ei, ei + E, bufB, E);
    k_finish<<<fb, 256, 0, stream>>>(bufB, dis, b2, bufB, N, 0);   // h2 in bufB

    // link-pred projections: A = h2@lpW1_top + lpb1 -> bufA ; B = h2@lpW1_bot -> bufB (in-place)
    k_gemm<64><<<gb, 256, 0, stream>>>(bufB, lpW1, lpb1, nullptr, bufA, nullptr, N);
    k_gemm<64><<<gb, 256, 0, stream>>>(bufB, lpW1 + 64 * 64, nullptr, nullptr, bufB, nullptr, N);

    // pair scoring
    k_pair<<<(P + 255) / 256, 256, 0, stream>>>(bufA, bufB, ep, lpW2, lpb2, out, P);
}

// Round 2
// 538.454 us; speedup vs baseline: 5.5739x; 5.5739x over previous
//
#include <hip/hip_runtime.h>
#include <cstddef>
#include <cstdint>

typedef float f4 __attribute__((ext_vector_type(4)));

#define HID 64

// ---------------- degree counting (int) ----------------
__global__ __launch_bounds__(256) void k_zero_i(int* p, int n) {
    int i = blockIdx.x * 256 + threadIdx.x;
    if (i < n) p[i] = 0;
}

__global__ __launch_bounds__(256) void k_count_i(const int* __restrict__ col,
                                                 int* __restrict__ cnt, int E) {
    int e = blockIdx.x * 256 + threadIdx.x;
    if (e < E) atomicAdd(&cnt[col[e]], 1);
}

__global__ __launch_bounds__(256) void k_dis(const int* __restrict__ cnt,
                                             float* __restrict__ dis, int N) {
    int i = blockIdx.x * 256 + threadIdx.x;
    if (i < N) dis[i] = rsqrtf(1.0f + (float)cnt[i]);   // +1 self-loop
}

// ---------------- exclusive scan (2-level) ----------------
__global__ __launch_bounds__(256) void k_scan1(const int* __restrict__ cnt,
                                               int* __restrict__ rowptr,
                                               int* __restrict__ bsum, int N) {
    __shared__ int s[256];
    int tid = threadIdx.x;
    int i = blockIdx.x * 256 + tid;
    int v = (i < N) ? cnt[i] : 0;
    s[tid] = v;
    __syncthreads();
    for (int off = 1; off < 256; off <<= 1) {
        int t = (tid >= off) ? s[tid - off] : 0;
        __syncthreads();
        s[tid] += t;
        __syncthreads();
    }
    if (i < N) rowptr[i] = s[tid] - v;            // exclusive within block
    if (tid == 255) bsum[blockIdx.x] = s[255];
}

__global__ __launch_bounds__(512) void k_scan2(int* bsum, int nb) {
    __shared__ int s[512];
    int tid = threadIdx.x;
    int v = (tid < nb) ? bsum[tid] : 0;
    s[tid] = v;
    __syncthreads();
    for (int off = 1; off < 512; off <<= 1) {
        int t = (tid >= off) ? s[tid - off] : 0;
        __syncthreads();
        s[tid] += t;
        __syncthreads();
    }
    if (tid < nb) bsum[tid] = s[tid] - v;         // exclusive block bases
}

__global__ __launch_bounds__(256) void k_scan3(int* __restrict__ rowptr,
                                               const int* __restrict__ bsum,
                                               int N, int E) {
    int i = blockIdx.x * 256 + threadIdx.x;
    if (i < N) rowptr[i] += bsum[i >> 8];
    if (i == 0) rowptr[N] = E;
}

// ---------------- CSR fill: srcs grouped by destination ----------------
__global__ __launch_bounds__(256) void k_fill(const int* __restrict__ row,
                                              const int* __restrict__ col,
                                              const int* __restrict__ rowptr,
                                              int* __restrict__ cursor,
                                              int* __restrict__ srcs, int E) {
    int e = blockIdx.x * 256 + threadIdx.x;
    if (e >= E) return;
    int c = col[e];
    int pos = rowptr[c] + atomicAdd(&cursor[c], 1);
    srcs[pos] = row[e];
}

// ---------------- GEMM: out = (X[N,K] @ W[K,64]) * scale[n] + bias[c] ----------------
template<int K>
__global__ __launch_bounds__(256) void k_gemm(
    const float* __restrict__ X, const float* __restrict__ W,
    const float* __restrict__ bias, const float* __restrict__ scale,
    float* __restrict__ out1, float* __restrict__ out2, int N)
{
    __shared__ float xs[64][68];
    __shared__ float ws[64][64];
    const int t = threadIdx.x;
    const int nbase = blockIdx.x * 64;
    const int c4 = (t & 15) * 4;
    const int n4 = (t >> 4) * 4;

    float acc[4][4] = {{0.f,0.f,0.f,0.f},{0.f,0.f,0.f,0.f},{0.f,0.f,0.f,0.f},{0.f,0.f,0.f,0.f}};

    const int node = t & 63;
    const int gn = nbase + node;
    const f4* Xrow = (gn < N) ? (const f4*)(X + (size_t)gn * K) : nullptr;
    const f4* W4 = (const f4*)W;

    for (int kt = 0; kt < K / 64; ++kt) {
        __syncthreads();
        #pragma unroll
        for (int i = 0; i < 4; ++i) {
            int k4r = i * 4 + (t >> 6);
            f4 v = {0.f, 0.f, 0.f, 0.f};
            if (Xrow) v = Xrow[kt * 16 + k4r];
            xs[k4r * 4 + 0][node] = v[0];
            xs[k4r * 4 + 1][node] = v[1];
            xs[k4r * 4 + 2][node] = v[2];
            xs[k4r * 4 + 3][node] = v[3];
        }
        #pragma unroll
        for (int i = 0; i < 4; ++i) {
            int f = i * 256 + t;
            int k = f >> 4, m4 = f & 15;
            *(f4*)&ws[k][m4 * 4] = W4[(size_t)(kt * 64 + k) * 16 + m4];
        }
        __syncthreads();
        #pragma unroll 8
        for (int k = 0; k < 64; ++k) {
            f4 xv = *(const f4*)&xs[k][n4];
            f4 wv = *(const f4*)&ws[k][c4];
            #pragma unroll
            for (int i2 = 0; i2 < 4; ++i2)
                #pragma unroll
                for (int j = 0; j < 4; ++j)
                    acc[i2][j] += xv[i2] * wv[j];
        }
    }

    #pragma unroll
    for (int i = 0; i < 4; ++i) {
        int g = nbase + n4 + i;
        if (g < N) {
            float s = scale ? scale[g] : 1.0f;
            f4 r;
            #pragma unroll
            for (int j = 0; j < 4; ++j) {
                float b = bias ? bias[c4 + j] : 0.0f;
                r[j] = acc[i][j] * s + b;
            }
            *(f4*)(out1 + (size_t)g * HID + c4) = r;
            if (out2) *(f4*)(out2 + (size_t)g * HID + c4) = r;
        }
    }
}

// ---------------- gather: out[c] = relu?((g[c] + sum g[src]) * dis[c] + bias) ----------------
// one 16-lane group per destination node; lane owns 4 contiguous features
__global__ __launch_bounds__(256) void k_gather(
    const float* __restrict__ g, const int* __restrict__ rowptr,
    const int* __restrict__ srcs, const float* __restrict__ dis,
    const float* __restrict__ bias, float* __restrict__ out, int N, int do_relu)
{
    int t = blockIdx.x * 256 + threadIdx.x;
    int node = t >> 4;
    if (node >= N) return;
    int c4 = (t & 15) * 4;

    f4 acc = *(const f4*)(g + (size_t)node * HID + c4);   // self-loop
    f4 acc2 = {0.f, 0.f, 0.f, 0.f};
    int s = rowptr[node], e = rowptr[node + 1];
    for (; s + 1 < e; s += 2) {
        int r0 = srcs[s], r1 = srcs[s + 1];
        acc  += *(const f4*)(g + (size_t)r0 * HID + c4);
        acc2 += *(const f4*)(g + (size_t)r1 * HID + c4);
    }
    if (s < e) {
        int r0 = srcs[s];
        acc += *(const f4*)(g + (size_t)r0 * HID + c4);
    }
    acc += acc2;

    float sc = dis[node];
    f4 r;
    #pragma unroll
    for (int j = 0; j < 4; ++j) {
        r[j] = acc[j] * sc + bias[c4 + j];
        if (do_relu) r[j] = r[j] > 0.f ? r[j] : 0.f;
    }
    *(f4*)(out + (size_t)node * HID + c4) = r;
}

// ---------------- fallback scatter path (atomics) ----------------
__global__ __launch_bounds__(256) void k_scatter(
    const float* __restrict__ g, const int* __restrict__ row, const int* __restrict__ col,
    float* __restrict__ acc, int E)
{
    int t = blockIdx.x * 256 + threadIdx.x;
    int e = t >> 4;
    if (e >= E) return;
    int c4 = (t & 15) * 4;
    int r = row[e], c = col[e];
    f4 v = *(const f4*)(g + (size_t)r * HID + c4);
    float* dst = acc + (size_t)c * HID + c4;
    unsafeAtomicAdd(dst + 0, v[0]);
    unsafeAtomicAdd(dst + 1, v[1]);
    unsafeAtomicAdd(dst + 2, v[2]);
    unsafeAtomicAdd(dst + 3, v[3]);
}

__global__ __launch_bounds__(256) void k_finish(
    const float* __restrict__ acc, const float* __restrict__ dis, const float* __restrict__ bias,
    float* __restrict__ out, int N, int do_relu)
{
    int t = blockIdx.x * 256 + threadIdx.x;
    if (t >= N * 16) return;
    int node = t >> 4, c4 = (t & 15) * 4;
    float s = dis[node];
    f4 v = *(const f4*)(acc + (size_t)t * 4);
    f4 r;
    #pragma unroll
    for (int j = 0; j < 4; ++j) {
        r[j] = v[j] * s + bias[c4 + j];
        if (do_relu) r[j] = r[j] > 0.f ? r[j] : 0.f;
    }
    *(f4*)(out + (size_t)t * 4) = r;
}

// ---------------- pair scorer ----------------
__global__ __launch_bounds__(256) void k_pair(
    const float* __restrict__ A, const float* __restrict__ B,
    const int* __restrict__ pairs, const float* __restrict__ w2, const float* __restrict__ b2,
    float* __restrict__ out, int P)
{
    __shared__ float w2s[64];
    if (threadIdx.x < 64) w2s[threadIdx.x] = w2[threadIdx.x];
    __syncthreads();
    int p = blockIdx.x * 256 + threadIdx.x;
    if (p >= P) return;
    int s = pairs[p], d = pairs[P + p];
    const f4* a4 = (const f4*)(A + (size_t)s * HID);
    const f4* b4 = (const f4*)(B + (size_t)d * HID);
    float acc = b2[0];
    #pragma unroll
    for (int i = 0; i < 16; ++i) {
        f4 av = a4[i], bv = b4[i];
        #pragma unroll
        for (int j = 0; j < 4; ++j) {
            float z = av[j] + bv[j];
            z = z > 0.f ? z : 0.f;
            acc += z * w2s[i * 4 + j];
        }
    }
    out[p] = 1.0f / (1.0f + __expf(-acc));
}

extern "C" void kernel_launch(void* const* d_in, const int* in_sizes, int n_in,
                              void* d_out, int out_size, void* d_ws, size_t ws_size,
                              hipStream_t stream)
{
    if (n_in < 11) return;
    const float* x    = (const float*)d_in[0];
    const int*   ei   = (const int*)d_in[1];
    const int*   ep   = (const int*)d_in[2];
    const float* W1   = (const float*)d_in[3];
    const float* b1   = (const float*)d_in[4];
    const float* W2   = (const float*)d_in[5];
    const float* b2   = (const float*)d_in[6];
    const float* lpW1 = (const float*)d_in[7];
    const float* lpb1 = (const float*)d_in[8];
    const float* lpW2 = (const float*)d_in[9];
    const float* lpb2 = (const float*)d_in[10];
    const int N = in_sizes[0] / 128;
    const int E = in_sizes[1] / 2;
    const int P = in_sizes[2] / 2;
    const int* erow = ei;
    const int* ecol = ei + E;
    float* out = (float*)d_out;

    const int nb  = (N + 255) / 256;        // scan blocks
    const int eb  = (E + 255) / 256;
    const int gb  = (N + 63) / 64;          // gemm blocks
    const int hb  = (N * 16 + 255) / 256;   // per-(node,f4) blocks

    // ---- workspace layout ----
    char* w = (char*)d_ws;
    float* dis   = (float*)w;                      w += (size_t)N * 4;
    int*   cnt   = (int*)w;                        w += (size_t)N * 4;
    // CSR extras
    int*   rowptr = (int*)w;                       char* w_csr = w + ((size_t)N + 1) * 4;
    int*   bsum   = (int*)w_csr;                   w_csr += 512 * 4;
    int*   srcs   = (int*)w_csr;                   w_csr += (size_t)E * 4;
    size_t off_csr = (size_t)(w_csr - (char*)d_ws);
    off_csr = (off_csr + 15) & ~(size_t)15;

    size_t need_csr = off_csr + 2 * (size_t)N * HID * 4;
    bool useCSR = (ws_size >= need_csr) && (nb <= 512);

    float* bufA;
    float* bufB;
    if (useCSR) {
        bufA = (float*)((char*)d_ws + off_csr);
    } else {
        size_t off_fb = ((size_t)(w - (char*)d_ws) + 15) & ~(size_t)15;
        if (ws_size < off_fb + 2 * (size_t)N * HID * 4) return;
        bufA = (float*)((char*)d_ws + off_fb);
    }
    bufB = bufA + (size_t)N * HID;

    // ---- degree + normalization ----
    k_zero_i<<<nb, 256, 0, stream>>>(cnt, N);
    k_count_i<<<eb, 256, 0, stream>>>(ecol, cnt, E);
    k_dis<<<nb, 256, 0, stream>>>(cnt, dis, N);

    if (useCSR) {
        // ---- CSR build ----
        k_scan1<<<nb, 256, 0, stream>>>(cnt, rowptr, bsum, N);
        k_scan2<<<1, 512, 0, stream>>>(bsum, nb);
        k_scan3<<<nb, 256, 0, stream>>>(rowptr, bsum, N, E);
        k_zero_i<<<nb, 256, 0, stream>>>(cnt, N);            // reuse as cursor
        k_fill<<<eb, 256, 0, stream>>>(erow, ecol, rowptr, cnt, srcs, E);

        // ---- layer 1 ----
        k_gemm<128><<<gb, 256, 0, stream>>>(x, W1, nullptr, dis, bufA, nullptr, N);
        k_gather<<<hb, 256, 0, stream>>>(bufA, rowptr, srcs, dis, b1, bufB, N, 1);
        // ---- layer 2 ----
        k_gemm<64><<<gb, 256, 0, stream>>>(bufB, W2, nullptr, dis, bufA, nullptr, N);
        k_gather<<<hb, 256, 0, stream>>>(bufA, rowptr, srcs, dis, b2, bufB, N, 0);
    } else {
        // ---- fallback: atomic scatter path ----
        const int sb = (int)(((size_t)E * 16 + 255) / 256);
        k_gemm<128><<<gb, 256, 0, stream>>>(x, W1, nullptr, dis, bufA, bufB, N);
        k_scatter<<<sb, 256, 0, stream>>>(bufA, erow, ecol, bufB, E);
        k_finish<<<hb, 256, 0, stream>>>(bufB, dis, b1, bufB, N, 1);
        k_gemm<64><<<gb, 256, 0, stream>>>(bufB, W2, nullptr, dis, bufA, bufB, N);
        k_scatter<<<sb, 256, 0, stream>>>(bufA, erow, ecol, bufB, E);
        k_finish<<<hb, 256, 0, stream>>>(bufB, dis, b2, bufB, N, 0);
    }

    // ---- link-pred projections ----
    k_gemm<64><<<gb, 256, 0, stream>>>(bufB, lpW1, lpb1, nullptr, bufA, nullptr, N);
    k_gemm<64><<<gb, 256, 0, stream>>>(bufB, lpW1 + 64 * 64, nullptr, nullptr, bufB, nullptr, N);

    // ---- pair scoring ----
    k_pair<<<(P + 255) / 256, 256, 0, stream>>>(bufA, bufB, ep, lpW2, lpb2, out, P);
}

// Round 3
// 360.328 us; speedup vs baseline: 8.3293x; 1.4943x over previous
//
#include <hip/hip_runtime.h>
#include <cstddef>
#include <cstdint>

typedef float f4 __attribute__((ext_vector_type(4)));

#define HID 64
#define EPB 8192   // edges per partition block

// ---------------- zero helper ----------------
__global__ __launch_bounds__(256) void k_zero_i(int* p, int n) {
    int i = blockIdx.x * 256 + threadIdx.x;
    if (i < n) p[i] = 0;
}

// ---------------- pass A: bucket histogram (bucket = col>>8) ----------------
__global__ __launch_bounds__(256) void k_partA(const int* __restrict__ col,
                                               int* __restrict__ gcount, int E, int NB) {
    __shared__ int h[512];
    int t = threadIdx.x;
    h[t] = 0; h[t + 256] = 0;
    __syncthreads();
    int e0 = blockIdx.x * EPB, e1 = min(E, e0 + EPB);
    for (int i = e0 + t; i < e1; i += 256) atomicAdd(&h[col[i] >> 8], 1);
    __syncthreads();
    for (int j = t; j < NB; j += 256) if (h[j]) atomicAdd(&gcount[j], h[j]);
}

// ---------------- scan bucket counts -> bases + cursors ----------------
__global__ __launch_bounds__(512) void k_scanB(const int* __restrict__ gcount,
                                               int* __restrict__ gbase,
                                               int* __restrict__ gcur, int NB, int E) {
    __shared__ int s[512];
    int t = threadIdx.x;
    int v = (t < NB) ? gcount[t] : 0;
    s[t] = v;
    __syncthreads();
    for (int o = 1; o < 512; o <<= 1) {
        int x = (t >= o) ? s[t - o] : 0;
        __syncthreads();
        s[t] += x;
        __syncthreads();
    }
    if (t < NB) { int ex = s[t] - v; gbase[t] = ex; gcur[t] = ex; }
    if (t == 0) gbase[NB] = E;
}

// ---------------- pass B: partition edges into bucket-grouped packed buf ----------------
// packed u32 = (col & 255) << 17 | row   (requires row < 2^17)
__global__ __launch_bounds__(256) void k_partB(const int* __restrict__ row,
                                               const int* __restrict__ col,
                                               int* __restrict__ gcur,
                                               unsigned* __restrict__ buf, int E) {
    __shared__ int h[512];
    __shared__ int lb[512];
    int t = threadIdx.x;
    h[t] = 0; h[t + 256] = 0;
    __syncthreads();
    int e0 = blockIdx.x * EPB, e1 = min(E, e0 + EPB);
    for (int i = e0 + t; i < e1; i += 256) atomicAdd(&h[col[i] >> 8], 1);
    __syncthreads();
    for (int j = t; j < 512; j += 256) {
        int c = h[j];
        lb[j] = c ? atomicAdd(&gcur[j], c) : 0;
        h[j] = 0;                       // same-thread reuse as local cursor
    }
    __syncthreads();
    for (int i = e0 + t; i < e1; i += 256) {
        int c = col[i];
        int b = c >> 8;
        int r = atomicAdd(&h[b], 1);
        buf[lb[b] + r] = ((unsigned)(c & 255) << 17) | (unsigned)row[i];
    }
}

// ---------------- pass C: per-bucket CSR finish (rowptr, dis, srcs) ----------------
__global__ __launch_bounds__(256) void k_passC(const unsigned* __restrict__ buf,
                                               const int* __restrict__ gbase,
                                               int* __restrict__ rowptr,
                                               int* __restrict__ srcs,
                                               float* __restrict__ dis, int N, int E) {
    __shared__ int hist[256];
    __shared__ int off[256];
    __shared__ int cur[256];
    int b = blockIdx.x, t = threadIdx.x;
    int e0 = gbase[b], e1 = gbase[b + 1];
    hist[t] = 0;
    __syncthreads();
    for (int i = e0 + t; i < e1; i += 256) atomicAdd(&hist[(buf[i] >> 17) & 255], 1);
    __syncthreads();
    int v = hist[t];
    off[t] = v;
    __syncthreads();
    for (int o = 1; o < 256; o <<= 1) {
        int x = (t >= o) ? off[t - o] : 0;
        __syncthreads();
        off[t] += x;
        __syncthreads();
    }
    int excl = off[t] - v;
    int c = b * 256 + t;
    if (c < N) {
        rowptr[c] = e0 + excl;
        dis[c] = rsqrtf(1.0f + (float)v);
    }
    if (b == (int)gridDim.x - 1 && t == 0) rowptr[N] = E;
    cur[t] = e0 + excl;
    __syncthreads();
    for (int i = e0 + t; i < e1; i += 256) {
        unsigned u = buf[i];
        int pos = atomicAdd(&cur[(u >> 17) & 255], 1);
        srcs[pos] = (int)(u & 0x1FFFF);
    }
}

// ---------------- GEMM: out = (X[N,K] @ W[K,64]) * scale[n] + bias[c] ----------------
template<int K>
__global__ __launch_bounds__(256) void k_gemm(
    const float* __restrict__ X, const float* __restrict__ W,
    const float* __restrict__ bias, const float* __restrict__ scale,
    float* __restrict__ out1, float* __restrict__ out2, int N)
{
    __shared__ float xs[64][68];
    __shared__ float ws[64][64];
    const int t = threadIdx.x;
    const int nbase = blockIdx.x * 64;
    const int c4 = (t & 15) * 4;
    const int n4 = (t >> 4) * 4;

    float acc[4][4] = {{0.f,0.f,0.f,0.f},{0.f,0.f,0.f,0.f},{0.f,0.f,0.f,0.f},{0.f,0.f,0.f,0.f}};

    const int node = t & 63;
    const int gn = nbase + node;
    const f4* Xrow = (gn < N) ? (const f4*)(X + (size_t)gn * K) : nullptr;
    const f4* W4 = (const f4*)W;

    for (int kt = 0; kt < K / 64; ++kt) {
        __syncthreads();
        #pragma unroll
        for (int i = 0; i < 4; ++i) {
            int k4r = i * 4 + (t >> 6);
            f4 v = {0.f, 0.f, 0.f, 0.f};
            if (Xrow) v = Xrow[kt * 16 + k4r];
            xs[k4r * 4 + 0][node] = v[0];
            xs[k4r * 4 + 1][node] = v[1];
            xs[k4r * 4 + 2][node] = v[2];
            xs[k4r * 4 + 3][node] = v[3];
        }
        #pragma unroll
        for (int i = 0; i < 4; ++i) {
            int f = i * 256 + t;
            int k = f >> 4, m4 = f & 15;
            *(f4*)&ws[k][m4 * 4] = W4[(size_t)(kt * 64 + k) * 16 + m4];
        }
        __syncthreads();
        #pragma unroll 8
        for (int k = 0; k < 64; ++k) {
            f4 xv = *(const f4*)&xs[k][n4];
            f4 wv = *(const f4*)&ws[k][c4];
            #pragma unroll
            for (int i2 = 0; i2 < 4; ++i2)
                #pragma unroll
                for (int j = 0; j < 4; ++j)
                    acc[i2][j] += xv[i2] * wv[j];
        }
    }

    #pragma unroll
    for (int i = 0; i < 4; ++i) {
        int g = nbase + n4 + i;
        if (g < N) {
            float s = scale ? scale[g] : 1.0f;
            f4 r;
            #pragma unroll
            for (int j = 0; j < 4; ++j) {
                float b = bias ? bias[c4 + j] : 0.0f;
                r[j] = acc[i][j] * s + b;
            }
            *(f4*)(out1 + (size_t)g * HID + c4) = r;
            if (out2) *(f4*)(out2 + (size_t)g * HID + c4) = r;
        }
    }
}

// ---------------- fused projection GEMM: A = X@Wt + b, B = X@Wb (K=64) ----------------
__global__ __launch_bounds__(256) void k_gemm2(
    const float* __restrict__ X, const float* __restrict__ W,   // W = lpW1 [128][64]
    const float* __restrict__ bias,
    float* __restrict__ outA, float* __restrict__ outB, int N)
{
    __shared__ float xs[64][68];
    __shared__ float ws[64][128];   // [k][c] top, [k][64+c] bottom
    const int t = threadIdx.x;
    const int nbase = blockIdx.x * 64;
    const int c4 = (t & 15) * 4;
    const int n4 = (t >> 4) * 4;

    float accA[4][4] = {{0.f,0.f,0.f,0.f},{0.f,0.f,0.f,0.f},{0.f,0.f,0.f,0.f},{0.f,0.f,0.f,0.f}};
    float accB[4][4] = {{0.f,0.f,0.f,0.f},{0.f,0.f,0.f,0.f},{0.f,0.f,0.f,0.f},{0.f,0.f,0.f,0.f}};

    const int node = t & 63;
    const int gn = nbase + node;
    const f4* Xrow = (gn < N) ? (const f4*)(X + (size_t)gn * HID) : nullptr;
    const f4* W4 = (const f4*)W;

    #pragma unroll
    for (int i = 0; i < 4; ++i) {
        int k4r = i * 4 + (t >> 6);
        f4 v = {0.f, 0.f, 0.f, 0.f};
        if (Xrow) v = Xrow[k4r];
        xs[k4r * 4 + 0][node] = v[0];
        xs[k4r * 4 + 1][node] = v[1];
        xs[k4r * 4 + 2][node] = v[2];
        xs[k4r * 4 + 3][node] = v[3];
    }
    #pragma unroll
    for (int i = 0; i < 8; ++i) {
        int f = i * 256 + t;            // f4 index into [128][16]
        int r = f >> 4, m4 = f & 15;
        int k = r & 63, half = (r >> 6) * 64;
        *(f4*)&ws[k][half + m4 * 4] = W4[f];
    }
    __syncthreads();
    #pragma unroll 8
    for (int k = 0; k < 64; ++k) {
        f4 xv = *(const f4*)&xs[k][n4];
        f4 wa = *(const f4*)&ws[k][c4];
        f4 wb = *(const f4*)&ws[k][64 + c4];
        #pragma unroll
        for (int i2 = 0; i2 < 4; ++i2)
            #pragma unroll
            for (int j = 0; j < 4; ++j) {
                accA[i2][j] += xv[i2] * wa[j];
                accB[i2][j] += xv[i2] * wb[j];
            }
    }

    #pragma unroll
    for (int i = 0; i < 4; ++i) {
        int g = nbase + n4 + i;
        if (g < N) {
            f4 ra, rb;
            #pragma unroll
            for (int j = 0; j < 4; ++j) {
                ra[j] = accA[i][j] + bias[c4 + j];
                rb[j] = accB[i][j];
            }
            *(f4*)(outA + (size_t)g * HID + c4) = ra;
            *(f4*)(outB + (size_t)g * HID + c4) = rb;
        }
    }
}

// ---------------- gather: out[c] = relu?((g[c] + sum g[src]) * dis[c] + bias) ----------------
__global__ __launch_bounds__(256) void k_gather(
    const float* __restrict__ g, const int* __restrict__ rowptr,
    const int* __restrict__ srcs, const float* __restrict__ dis,
    const float* __restrict__ bias, float* __restrict__ out, int N, int do_relu)
{
    int t = blockIdx.x * 256 + threadIdx.x;
    int node = t >> 4;
    if (node >= N) return;
    int c4 = (t & 15) * 4;

    f4 acc = *(const f4*)(g + (size_t)node * HID + c4);   // self-loop
    f4 acc2 = {0.f, 0.f, 0.f, 0.f};
    int s = rowptr[node], e = rowptr[node + 1];
    for (; s + 1 < e; s += 2) {
        int r0 = srcs[s], r1 = srcs[s + 1];
        acc  += *(const f4*)(g + (size_t)r0 * HID + c4);
        acc2 += *(const f4*)(g + (size_t)r1 * HID + c4);
    }
    if (s < e) acc += *(const f4*)(g + (size_t)srcs[s] * HID + c4);
    acc += acc2;

    float sc = dis[node];
    f4 r;
    #pragma unroll
    for (int j = 0; j < 4; ++j) {
        r[j] = acc[j] * sc + bias[c4 + j];
        if (do_relu) r[j] = r[j] > 0.f ? r[j] : 0.f;
    }
    *(f4*)(out + (size_t)node * HID + c4) = r;
}

// ---------------- fallback path kernels (atomic scatter) ----------------
__global__ __launch_bounds__(256) void k_count(const int* __restrict__ col,
                                               float* __restrict__ deg, int E) {
    int e = blockIdx.x * 256 + threadIdx.x;
    if (e < E) unsafeAtomicAdd(&deg[col[e]], 1.0f);
}
__global__ __launch_bounds__(256) void k_initf(float* p, float v, int n) {
    int i = blockIdx.x * 256 + threadIdx.x;
    if (i < n) p[i] = v;
}
__global__ __launch_bounds__(256) void k_rsqrt(float* deg, int N) {
    int i = blockIdx.x * 256 + threadIdx.x;
    if (i < N) deg[i] = rsqrtf(deg[i]);
}
__global__ __launch_bounds__(256) void k_scatter(
    const float* __restrict__ g, const int* __restrict__ row, const int* __restrict__ col,
    float* __restrict__ acc, int E)
{
    int t = blockIdx.x * 256 + threadIdx.x;
    int e = t >> 4;
    if (e >= E) return;
    int c4 = (t & 15) * 4;
    int r = row[e], c = col[e];
    f4 v = *(const f4*)(g + (size_t)r * HID + c4);
    float* dst = acc + (size_t)c * HID + c4;
    unsafeAtomicAdd(dst + 0, v[0]);
    unsafeAtomicAdd(dst + 1, v[1]);
    unsafeAtomicAdd(dst + 2, v[2]);
    unsafeAtomicAdd(dst + 3, v[3]);
}
__global__ __launch_bounds__(256) void k_finish(
    const float* __restrict__ acc, const float* __restrict__ dis, const float* __restrict__ bias,
    float* __restrict__ out, int N, int do_relu)
{
    int t = blockIdx.x * 256 + threadIdx.x;
    if (t >= N * 16) return;
    int node = t >> 4, c4 = (t & 15) * 4;
    float s = dis[node];
    f4 v = *(const f4*)(acc + (size_t)t * 4);
    f4 r;
    #pragma unroll
    for (int j = 0; j < 4; ++j) {
        r[j] = v[j] * s + bias[c4 + j];
        if (do_relu) r[j] = r[j] > 0.f ? r[j] : 0.f;
    }
    *(f4*)(out + (size_t)t * 4) = r;
}

// ---------------- pair scorer ----------------
__global__ __launch_bounds__(256) void k_pair(
    const float* __restrict__ A, const float* __restrict__ B,
    const int* __restrict__ pairs, const float* __restrict__ w2, const float* __restrict__ b2,
    float* __restrict__ out, int P)
{
    __shared__ float w2s[64];
    if (threadIdx.x < 64) w2s[threadIdx.x] = w2[threadIdx.x];
    __syncthreads();
    int p = blockIdx.x * 256 + threadIdx.x;
    if (p >= P) return;
    int s = pairs[p], d = pairs[P + p];
    const f4* a4 = (const f4*)(A + (size_t)s * HID);
    const f4* b4 = (const f4*)(B + (size_t)d * HID);
    float acc = b2[0];
    #pragma unroll
    for (int i = 0; i < 16; ++i) {
        f4 av = a4[i], bv = b4[i];
        #pragma unroll
        for (int j = 0; j < 4; ++j) {
            float z = av[j] + bv[j];
            z = z > 0.f ? z : 0.f;
            acc += z * w2s[i * 4 + j];
        }
    }
    out[p] = 1.0f / (1.0f + __expf(-acc));
}

extern "C" void kernel_launch(void* const* d_in, const int* in_sizes, int n_in,
                              void* d_out, int out_size, void* d_ws, size_t ws_size,
                              hipStream_t stream)
{
    if (n_in < 11) return;
    const float* x    = (const float*)d_in[0];
    const int*   ei   = (const int*)d_in[1];
    const int*   ep   = (const int*)d_in[2];
    const float* W1   = (const float*)d_in[3];
    const float* b1   = (const float*)d_in[4];
    const float* W2   = (const float*)d_in[5];
    const float* b2   = (const float*)d_in[6];
    const float* lpW1 = (const float*)d_in[7];
    const float* lpb1 = (const float*)d_in[8];
    const float* lpW2 = (const float*)d_in[9];
    const float* lpb2 = (const float*)d_in[10];
    const int N = in_sizes[0] / 128;
    const int E = in_sizes[1] / 2;
    const int P = in_sizes[2] / 2;
    const int* erow = ei;
    const int* ecol = ei + E;
    float* out = (float*)d_out;

    const int gb = (N + 63) / 64;           // gemm blocks
    const int hb = (N * 16 + 255) / 256;    // per-(node,f4) blocks
    const int NBk = (N + 255) / 256;        // buckets
    const int pa = (E + EPB - 1) / EPB;     // partition blocks

    // ---- workspace layout ----
    char* w = (char*)d_ws;
    float* dis    = (float*)w;  w += (size_t)N * 4;
    int*   rowptr = (int*)w;    w += ((size_t)N + 1) * 4;
    int*   gcount = (int*)w;    w += 512 * 4;
    int*   gbase  = (int*)w;    w += 513 * 4;
    int*   gcur   = (int*)w;    w += 512 * 4;
    int*   srcs   = (int*)w;    w += (size_t)E * 4;
    size_t off = ((size_t)(w - (char*)d_ws) + 255) & ~(size_t)255;
    float* bufA = (float*)((char*)d_ws + off);
    float* bufB = bufA + (size_t)N * HID;
    size_t need = off + 2 * (size_t)N * HID * 4;

    bool useNew = (N <= 131072) && (NBk <= 512) && (ws_size >= need) &&
                  ((size_t)E * 4 <= (size_t)N * HID * 4);

    if (useNew) {
        unsigned* pbuf = (unsigned*)bufA;   // partition buffer aliases bufA (dead until GEMM1)

        // ---- CSR build ----
        k_zero_i<<<2, 256, 0, stream>>>(gcount, 512);
        k_partA<<<pa, 256, 0, stream>>>(ecol, gcount, E, NBk);
        k_scanB<<<1, 512, 0, stream>>>(gcount, gbase, gcur, NBk, E);
        k_partB<<<pa, 256, 0, stream>>>(erow, ecol, gcur, pbuf, E);
        k_passC<<<NBk, 256, 0, stream>>>(pbuf, gbase, rowptr, srcs, dis, N, E);

        // ---- layer 1 ----
        k_gemm<128><<<gb, 256, 0, stream>>>(x, W1, nullptr, dis, bufA, nullptr, N);
        k_gather<<<hb, 256, 0, stream>>>(bufA, rowptr, srcs, dis, b1, bufB, N, 1);
        // ---- layer 2 ----
        k_gemm<64><<<gb, 256, 0, stream>>>(bufB, W2, nullptr, dis, bufA, nullptr, N);
        k_gather<<<hb, 256, 0, stream>>>(bufA, rowptr, srcs, dis, b2, bufB, N, 0);
        // ---- fused link-pred projections: A->bufA, B->bufB (in-place) ----
        k_gemm2<<<gb, 256, 0, stream>>>(bufB, lpW1, lpb1, bufA, bufB, N);
    } else {
        // ---- fallback: atomic scatter path ----
        size_t off_fb = (((size_t)N + (size_t)N + 1) * 4 + 255) & ~(size_t)255;
        if (ws_size < off_fb + 2 * (size_t)N * HID * 4) return;
        bufA = (float*)((char*)d_ws + off_fb);
        bufB = bufA + (size_t)N * HID;
        const int nb = (N + 255) / 256;
        const int eb = (E + 255) / 256;
        const int sb = (int)(((size_t)E * 16 + 255) / 256);
        k_initf<<<nb, 256, 0, stream>>>(dis, 1.0f, N);
        k_count<<<eb, 256, 0, stream>>>(ecol, dis, E);
        k_rsqrt<<<nb, 256, 0, stream>>>(dis, N);
        k_gemm<128><<<gb, 256, 0, stream>>>(x, W1, nullptr, dis, bufA, bufB, N);
        k_scatter<<<sb, 256, 0, stream>>>(bufA, erow, ecol, bufB, E);
        k_finish<<<hb, 256, 0, stream>>>(bufB, dis, b1, bufB, N, 1);
        k_gemm<64><<<gb, 256, 0, stream>>>(bufB, W2, nullptr, dis, bufA, bufB, N);
        k_scatter<<<sb, 256, 0, stream>>>(bufA, erow, ecol, bufB, E);
        k_finish<<<hb, 256, 0, stream>>>(bufB, dis, b2, bufB, N, 0);
        k_gemm2<<<gb, 256, 0, stream>>>(bufB, lpW1, lpb1, bufA, bufB, N);
    }

    // ---- pair scoring ----
    k_pair<<<(P + 255) / 256, 256, 0, stream>>>(bufA, bufB, ep, lpW2, lpb2, out, P);
}

// Round 4
// 267.005 us; speedup vs baseline: 11.2405x; 1.3495x over previous
//
#include <hip/hip_runtime.h>
#include <cstddef>
#include <cstdint>

typedef float f4 __attribute__((ext_vector_type(4)));
typedef unsigned short us4 __attribute__((ext_vector_type(4)));
typedef unsigned short us8 __attribute__((ext_vector_type(8)));

#define HID 64
#define EPB 8192   // edges per partition block

// ---------------- bf16 helpers (RNE) ----------------
__device__ inline float b2f(unsigned short u) {
    union { unsigned u32; float f; } x; x.u32 = (unsigned)u << 16; return x.f;
}
__device__ inline unsigned short f2b(float f) {
    union { float f; unsigned u; } x; x.f = f;
    unsigned r = 0x7FFFu + ((x.u >> 16) & 1u);
    return (unsigned short)((x.u + r) >> 16);
}
__device__ inline f4 b2f4(us4 h) { f4 r; r[0]=b2f(h[0]); r[1]=b2f(h[1]); r[2]=b2f(h[2]); r[3]=b2f(h[3]); return r; }
__device__ inline us4 f2b4(f4 v) { us4 r; r[0]=f2b(v[0]); r[1]=f2b(v[1]); r[2]=f2b(v[2]); r[3]=f2b(v[3]); return r; }

__device__ inline f4 ld4(const float* p) { return *(const f4*)p; }
__device__ inline f4 ld4(const unsigned short* p) { return b2f4(*(const us4*)p); }
__device__ inline void st4(float* p, f4 v) { *(f4*)p = v; }
__device__ inline void st4(unsigned short* p, f4 v) { *(us4*)p = f2b4(v); }

// ---------------- zero helper ----------------
__global__ __launch_bounds__(256) void k_zero_i(int* p, int n) {
    int i = blockIdx.x * 256 + threadIdx.x;
    if (i < n) p[i] = 0;
}

// ---------------- pass A: bucket histogram (bucket = col>>8) ----------------
__global__ __launch_bounds__(256) void k_partA(const int* __restrict__ col,
                                               int* __restrict__ gcount, int E, int NB) {
    __shared__ int h[512];
    int t = threadIdx.x;
    h[t] = 0; h[t + 256] = 0;
    __syncthreads();
    int e0 = blockIdx.x * EPB, e1 = min(E, e0 + EPB);
    for (int i = e0 + t; i < e1; i += 256) atomicAdd(&h[col[i] >> 8], 1);
    __syncthreads();
    for (int j = t; j < NB; j += 256) if (h[j]) atomicAdd(&gcount[j], h[j]);
}

// ---------------- scan bucket counts -> bases + cursors ----------------
__global__ __launch_bounds__(512) void k_scanB(const int* __restrict__ gcount,
                                               int* __restrict__ gbase,
                                               int* __restrict__ gcur, int NB, int E) {
    __shared__ int s[512];
    int t = threadIdx.x;
    int v = (t < NB) ? gcount[t] : 0;
    s[t] = v;
    __syncthreads();
    for (int o = 1; o < 512; o <<= 1) {
        int x = (t >= o) ? s[t - o] : 0;
        __syncthreads();
        s[t] += x;
        __syncthreads();
    }
    if (t < NB) { int ex = s[t] - v; gbase[t] = ex; gcur[t] = ex; }
    if (t == 0) gbase[NB] = E;
}

// ---------------- pass B: partition edges into bucket-grouped packed buf ----------------
// packed u32 = (col & 255) << 17 | row   (requires row < 2^17)
__global__ __launch_bounds__(256) void k_partB(const int* __restrict__ row,
                                               const int* __restrict__ col,
                                               int* __restrict__ gcur,
                                               unsigned* __restrict__ buf, int E) {
    __shared__ int h[512];
    __shared__ int lb[512];
    int t = threadIdx.x;
    h[t] = 0; h[t + 256] = 0;
    __syncthreads();
    int e0 = blockIdx.x * EPB, e1 = min(E, e0 + EPB);
    for (int i = e0 + t; i < e1; i += 256) atomicAdd(&h[col[i] >> 8], 1);
    __syncthreads();
    for (int j = t; j < 512; j += 256) {
        int c = h[j];
        lb[j] = c ? atomicAdd(&gcur[j], c) : 0;
        h[j] = 0;                       // same-thread reuse as local cursor
    }
    __syncthreads();
    for (int i = e0 + t; i < e1; i += 256) {
        int c = col[i];
        int b = c >> 8;
        int r = atomicAdd(&h[b], 1);
        buf[lb[b] + r] = ((unsigned)(c & 255) << 17) | (unsigned)row[i];
    }
}

// ---------------- pass C: per-bucket CSR finish (rowptr, dis, srcs) ----------------
__global__ __launch_bounds__(256) void k_passC(const unsigned* __restrict__ buf,
                                               const int* __restrict__ gbase,
                                               int* __restrict__ rowptr,
                                               int* __restrict__ srcs,
                                               float* __restrict__ dis, int N, int E) {
    __shared__ int hist[256];
    __shared__ int off[256];
    __shared__ int cur[256];
    int b = blockIdx.x, t = threadIdx.x;
    int e0 = gbase[b], e1 = gbase[b + 1];
    hist[t] = 0;
    __syncthreads();
    for (int i = e0 + t; i < e1; i += 256) atomicAdd(&hist[(buf[i] >> 17) & 255], 1);
    __syncthreads();
    int v = hist[t];
    off[t] = v;
    __syncthreads();
    for (int o = 1; o < 256; o <<= 1) {
        int x = (t >= o) ? off[t - o] : 0;
        __syncthreads();
        off[t] += x;
        __syncthreads();
    }
    int excl = off[t] - v;
    int c = b * 256 + t;
    if (c < N) {
        rowptr[c] = e0 + excl;
        dis[c] = rsqrtf(1.0f + (float)v);
    }
    if (b == (int)gridDim.x - 1 && t == 0) rowptr[N] = E;
    cur[t] = e0 + excl;
    __syncthreads();
    for (int i = e0 + t; i < e1; i += 256) {
        unsigned u = buf[i];
        int pos = atomicAdd(&cur[(u >> 17) & 255], 1);
        srcs[pos] = (int)(u & 0x1FFFF);
    }
}

// ---------------- GEMM: out = (X[N,K] @ W[K,64]) * scale[n] + bias[c] ----------------
template<int K, typename TIN, typename TOUT>
__global__ __launch_bounds__(256) void k_gemm(
    const TIN* __restrict__ X, const float* __restrict__ W,
    const float* __restrict__ bias, const float* __restrict__ scale,
    TOUT* __restrict__ out1, TOUT* __restrict__ out2, int N)
{
    __shared__ float xs[64][68];
    __shared__ float ws[64][64];
    const int t = threadIdx.x;
    const int nbase = blockIdx.x * 64;
    const int c4 = (t & 15) * 4;
    const int n4 = (t >> 4) * 4;

    float acc[4][4] = {{0.f,0.f,0.f,0.f},{0.f,0.f,0.f,0.f},{0.f,0.f,0.f,0.f},{0.f,0.f,0.f,0.f}};

    const int node = t & 63;
    const int gn = nbase + node;
    const TIN* Xrow = (gn < N) ? (X + (size_t)gn * K) : nullptr;
    const f4* W4 = (const f4*)W;

    for (int kt = 0; kt < K / 64; ++kt) {
        __syncthreads();
        #pragma unroll
        for (int i = 0; i < 4; ++i) {
            int k4r = i * 4 + (t >> 6);
            f4 v = {0.f, 0.f, 0.f, 0.f};
            if (Xrow) v = ld4(Xrow + (size_t)(kt * 16 + k4r) * 4);
            xs[k4r * 4 + 0][node] = v[0];
            xs[k4r * 4 + 1][node] = v[1];
            xs[k4r * 4 + 2][node] = v[2];
            xs[k4r * 4 + 3][node] = v[3];
        }
        #pragma unroll
        for (int i = 0; i < 4; ++i) {
            int f = i * 256 + t;
            int k = f >> 4, m4 = f & 15;
            *(f4*)&ws[k][m4 * 4] = W4[(size_t)(kt * 64 + k) * 16 + m4];
        }
        __syncthreads();
        #pragma unroll 8
        for (int k = 0; k < 64; ++k) {
            f4 xv = *(const f4*)&xs[k][n4];
            f4 wv = *(const f4*)&ws[k][c4];
            #pragma unroll
            for (int i2 = 0; i2 < 4; ++i2)
                #pragma unroll
                for (int j = 0; j < 4; ++j)
                    acc[i2][j] += xv[i2] * wv[j];
        }
    }

    #pragma unroll
    for (int i = 0; i < 4; ++i) {
        int g = nbase + n4 + i;
        if (g < N) {
            float s = scale ? scale[g] : 1.0f;
            f4 r;
            #pragma unroll
            for (int j = 0; j < 4; ++j) {
                float b = bias ? bias[c4 + j] : 0.0f;
                r[j] = acc[i][j] * s + b;
            }
            st4(out1 + (size_t)g * HID + c4, r);
            if (out2) st4(out2 + (size_t)g * HID + c4, r);
        }
    }
}

// ---------------- fused projection GEMM: A = X@Wt + b, B = X@Wb (K=64, bf16 out) ----------------
template<typename TIN>
__global__ __launch_bounds__(256) void k_gemm2(
    const TIN* __restrict__ X, const float* __restrict__ W,   // W = lpW1 [128][64]
    const float* __restrict__ bias,
    unsigned short* __restrict__ outA, unsigned short* __restrict__ outB, int N)
{
    __shared__ float xs[64][68];
    __shared__ float ws[64][128];
    const int t = threadIdx.x;
    const int nbase = blockIdx.x * 64;
    const int c4 = (t & 15) * 4;
    const int n4 = (t >> 4) * 4;

    float accA[4][4] = {{0.f,0.f,0.f,0.f},{0.f,0.f,0.f,0.f},{0.f,0.f,0.f,0.f},{0.f,0.f,0.f,0.f}};
    float accB[4][4] = {{0.f,0.f,0.f,0.f},{0.f,0.f,0.f,0.f},{0.f,0.f,0.f,0.f},{0.f,0.f,0.f,0.f}};

    const int node = t & 63;
    const int gn = nbase + node;
    const TIN* Xrow = (gn < N) ? (X + (size_t)gn * HID) : nullptr;
    const f4* W4 = (const f4*)W;

    #pragma unroll
    for (int i = 0; i < 4; ++i) {
        int k4r = i * 4 + (t >> 6);
        f4 v = {0.f, 0.f, 0.f, 0.f};
        if (Xrow) v = ld4(Xrow + (size_t)k4r * 4);
        xs[k4r * 4 + 0][node] = v[0];
        xs[k4r * 4 + 1][node] = v[1];
        xs[k4r * 4 + 2][node] = v[2];
        xs[k4r * 4 + 3][node] = v[3];
    }
    #pragma unroll
    for (int i = 0; i < 8; ++i) {
        int f = i * 256 + t;            // f4 index into [128][16]
        int r = f >> 4, m4 = f & 15;
        int k = r & 63, half = (r >> 6) * 64;
        *(f4*)&ws[k][half + m4 * 4] = W4[f];
    }
    __syncthreads();
    #pragma unroll 8
    for (int k = 0; k < 64; ++k) {
        f4 xv = *(const f4*)&xs[k][n4];
        f4 wa = *(const f4*)&ws[k][c4];
        f4 wb = *(const f4*)&ws[k][64 + c4];
        #pragma unroll
        for (int i2 = 0; i2 < 4; ++i2)
            #pragma unroll
            for (int j = 0; j < 4; ++j) {
                accA[i2][j] += xv[i2] * wa[j];
                accB[i2][j] += xv[i2] * wb[j];
            }
    }

    #pragma unroll
    for (int i = 0; i < 4; ++i) {
        int g = nbase + n4 + i;
        if (g < N) {
            f4 ra, rb;
            #pragma unroll
            for (int j = 0; j < 4; ++j) {
                ra[j] = accA[i][j] + bias[c4 + j];
                rb[j] = accB[i][j];
            }
            st4(outA + (size_t)g * HID + c4, ra);
            st4(outB + (size_t)g * HID + c4, rb);
        }
    }
}

// ---------------- gather (bf16 in/out, fp32 accum) ----------------
__global__ __launch_bounds__(256) void k_gather(
    const unsigned short* __restrict__ g, const int* __restrict__ rowptr,
    const int* __restrict__ srcs, const float* __restrict__ dis,
    const float* __restrict__ bias, unsigned short* __restrict__ out, int N, int do_relu)
{
    int t = blockIdx.x * 256 + threadIdx.x;
    int node = t >> 4;
    if (node >= N) return;
    int c4 = (t & 15) * 4;

    f4 acc = ld4(g + (size_t)node * HID + c4);   // self-loop
    f4 acc2 = {0.f, 0.f, 0.f, 0.f};
    int s = rowptr[node], e = rowptr[node + 1];
    for (; s + 1 < e; s += 2) {
        int r0 = srcs[s], r1 = srcs[s + 1];
        acc  += ld4(g + (size_t)r0 * HID + c4);
        acc2 += ld4(g + (size_t)r1 * HID + c4);
    }
    if (s < e) acc += ld4(g + (size_t)srcs[s] * HID + c4);
    acc += acc2;

    float sc = dis[node];
    f4 r;
    #pragma unroll
    for (int j = 0; j < 4; ++j) {
        r[j] = acc[j] * sc + bias[c4 + j];
        if (do_relu) r[j] = r[j] > 0.f ? r[j] : 0.f;
    }
    st4(out + (size_t)node * HID + c4, r);
}

// ---------------- fallback path kernels (fp32 atomic scatter) ----------------
__global__ __launch_bounds__(256) void k_count(const int* __restrict__ col,
                                               float* __restrict__ deg, int E) {
    int e = blockIdx.x * 256 + threadIdx.x;
    if (e < E) unsafeAtomicAdd(&deg[col[e]], 1.0f);
}
__global__ __launch_bounds__(256) void k_initf(float* p, float v, int n) {
    int i = blockIdx.x * 256 + threadIdx.x;
    if (i < n) p[i] = v;
}
__global__ __launch_bounds__(256) void k_rsqrt(float* deg, int N) {
    int i = blockIdx.x * 256 + threadIdx.x;
    if (i < N) deg[i] = rsqrtf(deg[i]);
}
__global__ __launch_bounds__(256) void k_scatter(
    const float* __restrict__ g, const int* __restrict__ row, const int* __restrict__ col,
    float* __restrict__ acc, int E)
{
    int t = blockIdx.x * 256 + threadIdx.x;
    int e = t >> 4;
    if (e >= E) return;
    int c4 = (t & 15) * 4;
    int r = row[e], c = col[e];
    f4 v = *(const f4*)(g + (size_t)r * HID + c4);
    float* dst = acc + (size_t)c * HID + c4;
    unsafeAtomicAdd(dst + 0, v[0]);
    unsafeAtomicAdd(dst + 1, v[1]);
    unsafeAtomicAdd(dst + 2, v[2]);
    unsafeAtomicAdd(dst + 3, v[3]);
}
__global__ __launch_bounds__(256) void k_finish(
    const float* __restrict__ acc, const float* __restrict__ dis, const float* __restrict__ bias,
    float* __restrict__ out, int N, int do_relu)
{
    int t = blockIdx.x * 256 + threadIdx.x;
    if (t >= N * 16) return;
    int node = t >> 4, c4 = (t & 15) * 4;
    float s = dis[node];
    f4 v = *(const f4*)(acc + (size_t)t * 4);
    f4 r;
    #pragma unroll
    for (int j = 0; j < 4; ++j) {
        r[j] = v[j] * s + bias[c4 + j];
        if (do_relu) r[j] = r[j] > 0.f ? r[j] : 0.f;
    }
    *(f4*)(out + (size_t)t * 4) = r;
}

// ---------------- pair scorer (bf16 A/B) ----------------
__global__ __launch_bounds__(256) void k_pair(
    const unsigned short* __restrict__ A, const unsigned short* __restrict__ B,
    const int* __restrict__ pairs, const float* __restrict__ w2, const float* __restrict__ b2,
    float* __restrict__ out, int P)
{
    __shared__ float w2s[64];
    if (threadIdx.x < 64) w2s[threadIdx.x] = w2[threadIdx.x];
    __syncthreads();
    int p = blockIdx.x * 256 + threadIdx.x;
    if (p >= P) return;
    int s = pairs[p], d = pairs[P + p];
    const us8* a8 = (const us8*)(A + (size_t)s * HID);
    const us8* b8 = (const us8*)(B + (size_t)d * HID);
    float acc = b2[0];
    #pragma unroll
    for (int i = 0; i < 8; ++i) {
        us8 av = a8[i], bv = b8[i];
        #pragma unroll
        for (int j = 0; j < 8; ++j) {
            float z = b2f(av[j]) + b2f(bv[j]);
            z = z > 0.f ? z : 0.f;
            acc += z * w2s[i * 8 + j];
        }
    }
    out[p] = 1.0f / (1.0f + __expf(-acc));
}

extern "C" void kernel_launch(void* const* d_in, const int* in_sizes, int n_in,
                              void* d_out, int out_size, void* d_ws, size_t ws_size,
                              hipStream_t stream)
{
    if (n_in < 11) return;
    const float* x    = (const float*)d_in[0];
    const int*   ei   = (const int*)d_in[1];
    const int*   ep   = (const int*)d_in[2];
    const float* W1   = (const float*)d_in[3];
    const float* b1   = (const float*)d_in[4];
    const float* W2   = (const float*)d_in[5];
    const float* b2   = (const float*)d_in[6];
    const float* lpW1 = (const float*)d_in[7];
    const float* lpb1 = (const float*)d_in[8];
    const float* lpW2 = (const float*)d_in[9];
    const float* lpb2 = (const float*)d_in[10];
    const int N = in_sizes[0] / 128;
    const int E = in_sizes[1] / 2;
    const int P = in_sizes[2] / 2;
    const int* erow = ei;
    const int* ecol = ei + E;
    float* out = (float*)d_out;

    const int gb = (N + 63) / 64;           // gemm blocks
    const int hb = (N * 16 + 255) / 256;    // per-(node,f4) blocks
    const int NBk = (N + 255) / 256;        // buckets
    const int pa = (E + EPB - 1) / EPB;     // partition blocks

    // ---- workspace layout ----
    char* w = (char*)d_ws;
    float* dis    = (float*)w;  w += (size_t)N * 4;
    int*   rowptr = (int*)w;    w += ((size_t)N + 1) * 4;
    int*   gcount = (int*)w;    w += 512 * 4;
    int*   gbase  = (int*)w;    w += 513 * 4;
    int*   gcur   = (int*)w;    w += 512 * 4;
    int*   srcs   = (int*)w;    w += (size_t)E * 4;
    size_t off = ((size_t)(w - (char*)d_ws) + 255) & ~(size_t)255;

    size_t featB = (size_t)N * HID * 2;     // bf16 feature buffer bytes
    unsigned short* bufA = (unsigned short*)((char*)d_ws + off);
    unsigned short* bufB = bufA + (size_t)N * HID;
    size_t need = off + 2 * featB;

    bool useNew = (N <= 131072) && (NBk <= 512) && (ws_size >= need) &&
                  ((size_t)E * 4 <= featB);

    if (useNew) {
        unsigned* pbuf = (unsigned*)bufA;   // partition buffer aliases bufA (dead until GEMM1)

        // ---- CSR build ----
        k_zero_i<<<2, 256, 0, stream>>>(gcount, 512);
        k_partA<<<pa, 256, 0, stream>>>(ecol, gcount, E, NBk);
        k_scanB<<<1, 512, 0, stream>>>(gcount, gbase, gcur, NBk, E);
        k_partB<<<pa, 256, 0, stream>>>(erow, ecol, gcur, pbuf, E);
        k_passC<<<NBk, 256, 0, stream>>>(pbuf, gbase, rowptr, srcs, dis, N, E);

        // ---- layer 1 ----
        k_gemm<128, float, unsigned short><<<gb, 256, 0, stream>>>(x, W1, nullptr, dis, bufA, nullptr, N);
        k_gather<<<hb, 256, 0, stream>>>(bufA, rowptr, srcs, dis, b1, bufB, N, 1);
        // ---- layer 2 ----
        k_gemm<64, unsigned short, unsigned short><<<gb, 256, 0, stream>>>(bufB, W2, nullptr, dis, bufA, nullptr, N);
        k_gather<<<hb, 256, 0, stream>>>(bufA, rowptr, srcs, dis, b2, bufB, N, 0);
        // ---- fused link-pred projections: A->bufA, B->bufB (in-place safe) ----
        k_gemm2<unsigned short><<<gb, 256, 0, stream>>>(bufB, lpW1, lpb1, bufA, bufB, N);

        k_pair<<<(P + 255) / 256, 256, 0, stream>>>(bufA, bufB, ep, lpW2, lpb2, out, P);
    } else {
        // ---- fallback: fp32 atomic scatter path ----
        size_t off_fb = (((size_t)N + (size_t)N + 1) * 4 + 255) & ~(size_t)255;
        float* fA = (float*)((char*)d_ws + off_fb);
        float* fB = fA + (size_t)N * HID;
        if (ws_size < off_fb + 2 * (size_t)N * HID * 4) return;
        const int nb = (N + 255) / 256;
        const int eb = (E + 255) / 256;
        const int sb = (int)(((size_t)E * 16 + 255) / 256);
        k_initf<<<nb, 256, 0, stream>>>(dis, 1.0f, N);
        k_count<<<eb, 256, 0, stream>>>(ecol, dis, E);
        k_rsqrt<<<nb, 256, 0, stream>>>(dis, N);
        k_gemm<128, float, float><<<gb, 256, 0, stream>>>(x, W1, nullptr, dis, fA, fB, N);
        k_scatter<<<sb, 256, 0, stream>>>(fA, erow, ecol, fB, E);
        k_finish<<<hb, 256, 0, stream>>>(fB, dis, b1, fB, N, 1);
        k_gemm<64, float, float><<<gb, 256, 0, stream>>>(fB, W2, nullptr, dis, fA, fB, N);
        k_scatter<<<sb, 256, 0, stream>>>(fA, erow, ecol, fB, E);
        k_finish<<<hb, 256, 0, stream>>>(fB, dis, b2, fB, N, 0);
        // bf16 A/B carved inside fA (g2 region, dead after scatter)
        unsigned short* bA = (unsigned short*)fA;
        unsigned short* bB = bA + (size_t)N * HID;
        k_gemm2<float><<<gb, 256, 0, stream>>>(fB, lpW1, lpb1, bA, bB, N);
        k_pair<<<(P + 255) / 256, 256, 0, stream>>>(bA, bB, ep, lpW2, lpb2, out, P);
    }
}

// Round 5
// 256.057 us; speedup vs baseline: 11.7211x; 1.0428x over previous
//
#include <hip/hip_runtime.h>
#include <cstddef>
#include <cstdint>

typedef float f4 __attribute__((ext_vector_type(4)));
typedef unsigned short us4 __attribute__((ext_vector_type(4)));

#define HID 64
#define EPB 2048   // edges per partition block
#define CAP 8192   // slots per bucket in partition buffer

// ---------------- bf16 helpers (RNE) ----------------
__device__ inline float b2f(unsigned short u) {
    union { unsigned u32; float f; } x; x.u32 = (unsigned)u << 16; return x.f;
}
__device__ inline unsigned short f2b(float f) {
    union { float f; unsigned u; } x; x.f = f;
    unsigned r = 0x7FFFu + ((x.u >> 16) & 1u);
    return (unsigned short)((x.u + r) >> 16);
}
__device__ inline f4 b2f4(us4 h) { f4 r; r[0]=b2f(h[0]); r[1]=b2f(h[1]); r[2]=b2f(h[2]); r[3]=b2f(h[3]); return r; }
__device__ inline us4 f2b4(f4 v) { us4 r; r[0]=f2b(v[0]); r[1]=f2b(v[1]); r[2]=f2b(v[2]); r[3]=f2b(v[3]); return r; }

__device__ inline f4 ld4(const float* p) { return *(const f4*)p; }
__device__ inline f4 ld4(const unsigned short* p) { return b2f4(*(const us4*)p); }
__device__ inline void st4(float* p, f4 v) { *(f4*)p = v; }
__device__ inline void st4(unsigned short* p, f4 v) { *(us4*)p = f2b4(v); }

// ---------------- init bucket cursors: gcur[b] = b*CAP ----------------
__global__ __launch_bounds__(256) void k_initcur(int* gcur) {
    int i = blockIdx.x * 256 + threadIdx.x;
    if (i < 512) gcur[i] = i * CAP;
}

// ---------------- partition edges into fixed-capacity buckets ----------------
// packed u32 = (col & 255) << 17 | row   (requires row < 2^17)
__global__ __launch_bounds__(256) void k_partB(const int* __restrict__ row,
                                               const int* __restrict__ col,
                                               int* __restrict__ gcur,
                                               unsigned* __restrict__ buf, int E) {
    __shared__ int h[512];
    __shared__ int lb[512];
    int t = threadIdx.x;
    h[t] = 0; h[t + 256] = 0;
    __syncthreads();
    int e0 = blockIdx.x * EPB, e1 = min(E, e0 + EPB);
    for (int i = e0 + t; i < e1; i += 256) atomicAdd(&h[col[i] >> 8], 1);
    __syncthreads();
    for (int j = t; j < 512; j += 256) {
        int c = h[j];
        lb[j] = c ? atomicAdd(&gcur[j], c) : 0;
        h[j] = 0;                       // same-thread reuse as local cursor
    }
    __syncthreads();
    for (int i = e0 + t; i < e1; i += 256) {
        int c = col[i];
        int b = c >> 8;
        int r = atomicAdd(&h[b], 1);
        buf[lb[b] + r] = ((unsigned)(c & 255) << 17) | (unsigned)row[i];
    }
}

// ---------------- scan bucket counts (from gcur) -> gbase ----------------
__global__ __launch_bounds__(512) void k_scanB(const int* __restrict__ gcur,
                                               int* __restrict__ gbase, int NB, int E) {
    __shared__ int s[512];
    int t = threadIdx.x;
    int v = (t < NB) ? (gcur[t] - t * CAP) : 0;
    s[t] = v;
    __syncthreads();
    for (int o = 1; o < 512; o <<= 1) {
        int x = (t >= o) ? s[t - o] : 0;
        __syncthreads();
        s[t] += x;
        __syncthreads();
    }
    if (t < NB) gbase[t] = s[t] - v;
    if (t == 0) gbase[NB] = E;
}

// ---------------- pass C: per-bucket CSR finish (rowptr, dis, srcs) ----------------
__global__ __launch_bounds__(256) void k_passC(const unsigned* __restrict__ buf,
                                               const int* __restrict__ gcur,
                                               const int* __restrict__ gbase,
                                               int* __restrict__ rowptr,
                                               int* __restrict__ srcs,
                                               float* __restrict__ dis, int N, int E) {
    __shared__ int hist[256];
    __shared__ int off[256];
    __shared__ int cur[256];
    int b = blockIdx.x, t = threadIdx.x;
    int r0 = b * CAP, r1 = gcur[b];
    int w0 = gbase[b];
    hist[t] = 0;
    __syncthreads();
    for (int i = r0 + t; i < r1; i += 256) atomicAdd(&hist[(buf[i] >> 17) & 255], 1);
    __syncthreads();
    int v = hist[t];
    off[t] = v;
    __syncthreads();
    for (int o = 1; o < 256; o <<= 1) {
        int x = (t >= o) ? off[t - o] : 0;
        __syncthreads();
        off[t] += x;
        __syncthreads();
    }
    int excl = off[t] - v;
    int c = b * 256 + t;
    if (c < N) {
        rowptr[c] = w0 + excl;
        dis[c] = rsqrtf(1.0f + (float)v);
    }
    if (b == (int)gridDim.x - 1 && t == 0) rowptr[N] = E;
    cur[t] = w0 + excl;
    __syncthreads();
    for (int i = r0 + t; i < r1; i += 256) {
        unsigned u = buf[i];
        int pos = atomicAdd(&cur[(u >> 17) & 255], 1);
        srcs[pos] = (int)(u & 0x1FFFF);
    }
}

// ---------------- GEMM: out = (X[N,K] @ W[K,64]) * scale[n] + bias[c] ----------------
template<int K, typename TIN, typename TOUT>
__global__ __launch_bounds__(256) void k_gemm(
    const TIN* __restrict__ X, const float* __restrict__ W,
    const float* __restrict__ bias, const float* __restrict__ scale,
    TOUT* __restrict__ out1, TOUT* __restrict__ out2, int N)
{
    __shared__ float xs[64][68];
    __shared__ float ws[64][64];
    const int t = threadIdx.x;
    const int nbase = blockIdx.x * 64;
    const int c4 = (t & 15) * 4;
    const int n4 = (t >> 4) * 4;

    float acc[4][4] = {{0.f,0.f,0.f,0.f},{0.f,0.f,0.f,0.f},{0.f,0.f,0.f,0.f},{0.f,0.f,0.f,0.f}};

    const int node = t & 63;
    const int gn = nbase + node;
    const TIN* Xrow = (gn < N) ? (X + (size_t)gn * K) : nullptr;
    const f4* W4 = (const f4*)W;

    for (int kt = 0; kt < K / 64; ++kt) {
        __syncthreads();
        #pragma unroll
        for (int i = 0; i < 4; ++i) {
            int k4r = i * 4 + (t >> 6);
            f4 v = {0.f, 0.f, 0.f, 0.f};
            if (Xrow) v = ld4(Xrow + (size_t)(kt * 16 + k4r) * 4);
            xs[k4r * 4 + 0][node] = v[0];
            xs[k4r * 4 + 1][node] = v[1];
            xs[k4r * 4 + 2][node] = v[2];
            xs[k4r * 4 + 3][node] = v[3];
        }
        #pragma unroll
        for (int i = 0; i < 4; ++i) {
            int f = i * 256 + t;
            int k = f >> 4, m4 = f & 15;
            *(f4*)&ws[k][m4 * 4] = W4[(size_t)(kt * 64 + k) * 16 + m4];
        }
        __syncthreads();
        #pragma unroll 8
        for (int k = 0; k < 64; ++k) {
            f4 xv = *(const f4*)&xs[k][n4];
            f4 wv = *(const f4*)&ws[k][c4];
            #pragma unroll
            for (int i2 = 0; i2 < 4; ++i2)
                #pragma unroll
                for (int j = 0; j < 4; ++j)
                    acc[i2][j] += xv[i2] * wv[j];
        }
    }

    #pragma unroll
    for (int i = 0; i < 4; ++i) {
        int g = nbase + n4 + i;
        if (g < N) {
            float s = scale ? scale[g] : 1.0f;
            f4 r;
            #pragma unroll
            for (int j = 0; j < 4; ++j) {
                float b = bias ? bias[c4 + j] : 0.0f;
                r[j] = acc[i][j] * s + b;
            }
            st4(out1 + (size_t)g * HID + c4, r);
            if (out2) st4(out2 + (size_t)g * HID + c4, r);
        }
    }
}

// ---------------- fused projection GEMM: A = X@Wt + b, B = X@Wb (K=64, bf16 out) ----------------
template<typename TIN>
__global__ __launch_bounds__(256) void k_gemm2(
    const TIN* __restrict__ X, const float* __restrict__ W,   // W = lpW1 [128][64]
    const float* __restrict__ bias,
    unsigned short* __restrict__ outA, unsigned short* __restrict__ outB, int N)
{
    __shared__ float xs[64][68];
    __shared__ float ws[64][128];
    const int t = threadIdx.x;
    const int nbase = blockIdx.x * 64;
    const int c4 = (t & 15) * 4;
    const int n4 = (t >> 4) * 4;

    float accA[4][4] = {{0.f,0.f,0.f,0.f},{0.f,0.f,0.f,0.f},{0.f,0.f,0.f,0.f},{0.f,0.f,0.f,0.f}};
    float accB[4][4] = {{0.f,0.f,0.f,0.f},{0.f,0.f,0.f,0.f},{0.f,0.f,0.f,0.f},{0.f,0.f,0.f,0.f}};

    const int node = t & 63;
    const int gn = nbase + node;
    const TIN* Xrow = (gn < N) ? (X + (size_t)gn * HID) : nullptr;
    const f4* W4 = (const f4*)W;

    #pragma unroll
    for (int i = 0; i < 4; ++i) {
        int k4r = i * 4 + (t >> 6);
        f4 v = {0.f, 0.f, 0.f, 0.f};
        if (Xrow) v = ld4(Xrow + (size_t)k4r * 4);
        xs[k4r * 4 + 0][node] = v[0];
        xs[k4r * 4 + 1][node] = v[1];
        xs[k4r * 4 + 2][node] = v[2];
        xs[k4r * 4 + 3][node] = v[3];
    }
    #pragma unroll
    for (int i = 0; i < 8; ++i) {
        int f = i * 256 + t;            // f4 index into [128][16]
        int r = f >> 4, m4 = f & 15;
        int k = r & 63, half = (r >> 6) * 64;
        *(f4*)&ws[k][half + m4 * 4] = W4[f];
    }
    __syncthreads();
    #pragma unroll 8
    for (int k = 0; k < 64; ++k) {
        f4 xv = *(const f4*)&xs[k][n4];
        f4 wa = *(const f4*)&ws[k][c4];
        f4 wb = *(const f4*)&ws[k][64 + c4];
        #pragma unroll
        for (int i2 = 0; i2 < 4; ++i2)
            #pragma unroll
            for (int j = 0; j < 4; ++j) {
                accA[i2][j] += xv[i2] * wa[j];
                accB[i2][j] += xv[i2] * wb[j];
            }
    }

    #pragma unroll
    for (int i = 0; i < 4; ++i) {
        int g = nbase + n4 + i;
        if (g < N) {
            f4 ra, rb;
            #pragma unroll
            for (int j = 0; j < 4; ++j) {
                ra[j] = accA[i][j] + bias[c4 + j];
                rb[j] = accB[i][j];
            }
            st4(outA + (size_t)g * HID + c4, ra);
            st4(outB + (size_t)g * HID + c4, rb);
        }
    }
}

// ---------------- gather (bf16 in/out, fp32 accum) ----------------
__global__ __launch_bounds__(256) void k_gather(
    const unsigned short* __restrict__ g, const int* __restrict__ rowptr,
    const int* __restrict__ srcs, const float* __restrict__ dis,
    const float* __restrict__ bias, unsigned short* __restrict__ out, int N, int do_relu)
{
    int t = blockIdx.x * 256 + threadIdx.x;
    int node = t >> 4;
    if (node >= N) return;
    int c4 = (t & 15) * 4;

    f4 acc = ld4(g + (size_t)node * HID + c4);   // self-loop
    f4 acc2 = {0.f, 0.f, 0.f, 0.f};
    int s = rowptr[node], e = rowptr[node + 1];
    for (; s + 1 < e; s += 2) {
        int r0 = srcs[s], r1 = srcs[s + 1];
        acc  += ld4(g + (size_t)r0 * HID + c4);
        acc2 += ld4(g + (size_t)r1 * HID + c4);
    }
    if (s < e) acc += ld4(g + (size_t)srcs[s] * HID + c4);
    acc += acc2;

    float sc = dis[node];
    f4 r;
    #pragma unroll
    for (int j = 0; j < 4; ++j) {
        r[j] = acc[j] * sc + bias[c4 + j];
        if (do_relu) r[j] = r[j] > 0.f ? r[j] : 0.f;
    }
    st4(out + (size_t)node * HID + c4, r);
}

// ---------------- fallback path kernels (fp32 atomic scatter) ----------------
__global__ __launch_bounds__(256) void k_count(const int* __restrict__ col,
                                               float* __restrict__ deg, int E) {
    int e = blockIdx.x * 256 + threadIdx.x;
    if (e < E) unsafeAtomicAdd(&deg[col[e]], 1.0f);
}
__global__ __launch_bounds__(256) void k_initf(float* p, float v, int n) {
    int i = blockIdx.x * 256 + threadIdx.x;
    if (i < n) p[i] = v;
}
__global__ __launch_bounds__(256) void k_rsqrt(float* deg, int N) {
    int i = blockIdx.x * 256 + threadIdx.x;
    if (i < N) deg[i] = rsqrtf(deg[i]);
}
__global__ __launch_bounds__(256) void k_scatter(
    const float* __restrict__ g, const int* __restrict__ row, const int* __restrict__ col,
    float* __restrict__ acc, int E)
{
    int t = blockIdx.x * 256 + threadIdx.x;
    int e = t >> 4;
    if (e >= E) return;
    int c4 = (t & 15) * 4;
    int r = row[e], c = col[e];
    f4 v = *(const f4*)(g + (size_t)r * HID + c4);
    float* dst = acc + (size_t)c * HID + c4;
    unsafeAtomicAdd(dst + 0, v[0]);
    unsafeAtomicAdd(dst + 1, v[1]);
    unsafeAtomicAdd(dst + 2, v[2]);
    unsafeAtomicAdd(dst + 3, v[3]);
}
__global__ __launch_bounds__(256) void k_finish(
    const float* __restrict__ acc, const float* __restrict__ dis, const float* __restrict__ bias,
    float* __restrict__ out, int N, int do_relu)
{
    int t = blockIdx.x * 256 + threadIdx.x;
    if (t >= N * 16) return;
    int node = t >> 4, c4 = (t & 15) * 4;
    float s = dis[node];
    f4 v = *(const f4*)(acc + (size_t)t * 4);
    f4 r;
    #pragma unroll
    for (int j = 0; j < 4; ++j) {
        r[j] = v[j] * s + bias[c4 + j];
        if (do_relu) r[j] = r[j] > 0.f ? r[j] : 0.f;
    }
    *(f4*)(out + (size_t)t * 4) = r;
}

// ---------------- pair scorer: 16 lanes per pair, coalesced 128B row loads ----------------
__global__ __launch_bounds__(256) void k_pair(
    const unsigned short* __restrict__ A, const unsigned short* __restrict__ B,
    const int* __restrict__ pairs, const float* __restrict__ w2, const float* __restrict__ b2,
    float* __restrict__ out, int P)
{
    __shared__ float w2s[64];
    if (threadIdx.x < 64) w2s[threadIdx.x] = w2[threadIdx.x];
    __syncthreads();
    int g = blockIdx.x * 256 + threadIdx.x;
    int p = g >> 4;
    if (p >= P) return;
    int l = g & 15;            // lane within pair group
    int sub = l & 7;           // 16B chunk id within row
    int isB = l >> 3;
    int node = isB ? pairs[P + p] : pairs[p];
    const unsigned short* basep = (isB ? B : A) + (size_t)node * HID + sub * 8;
    int4 own = *(const int4*)basep;
    int4 oth;
    oth.x = __shfl_xor(own.x, 8, 16);
    oth.y = __shfl_xor(own.y, 8, 16);
    oth.z = __shfl_xor(own.z, 8, 16);
    oth.w = __shfl_xor(own.w, 8, 16);
    const float* wv = &w2s[sub * 8];
    int o[4] = {own.x, own.y, own.z, own.w};
    int q[4] = {oth.x, oth.y, oth.z, oth.w};
    float acc = 0.f;
    #pragma unroll
    for (int k = 0; k < 4; ++k) {
        float alo = __uint_as_float((unsigned)o[k] << 16);
        float ahi = __uint_as_float((unsigned)o[k] & 0xFFFF0000u);
        float blo = __uint_as_float((unsigned)q[k] << 16);
        float bhi = __uint_as_float((unsigned)q[k] & 0xFFFF0000u);
        float zlo = alo + blo; zlo = zlo > 0.f ? zlo : 0.f;
        float zhi = ahi + bhi; zhi = zhi > 0.f ? zhi : 0.f;
        acc += zlo * wv[2 * k] + zhi * wv[2 * k + 1];
    }
    acc += __shfl_xor(acc, 1, 16);
    acc += __shfl_xor(acc, 2, 16);
    acc += __shfl_xor(acc, 4, 16);
    if (l == 0) out[p] = 1.0f / (1.0f + __expf(-(acc + b2[0])));
}

extern "C" void kernel_launch(void* const* d_in, const int* in_sizes, int n_in,
                              void* d_out, int out_size, void* d_ws, size_t ws_size,
                              hipStream_t stream)
{
    if (n_in < 11) return;
    const float* x    = (const float*)d_in[0];
    const int*   ei   = (const int*)d_in[1];
    const int*   ep   = (const int*)d_in[2];
    const float* W1   = (const float*)d_in[3];
    const float* b1   = (const float*)d_in[4];
    const float* W2   = (const float*)d_in[5];
    const float* b2   = (const float*)d_in[6];
    const float* lpW1 = (const float*)d_in[7];
    const float* lpb1 = (const float*)d_in[8];
    const float* lpW2 = (const float*)d_in[9];
    const float* lpb2 = (const float*)d_in[10];
    const int N = in_sizes[0] / 128;
    const int E = in_sizes[1] / 2;
    const int P = in_sizes[2] / 2;
    const int* erow = ei;
    const int* ecol = ei + E;
    float* out = (float*)d_out;

    const int gb = (N + 63) / 64;           // gemm blocks
    const int hb = (N * 16 + 255) / 256;    // per-(node,f4) blocks
    const int NBk = (N + 255) / 256;        // buckets
    const int pa = (E + EPB - 1) / EPB;     // partition blocks
    const int pb = (int)(((size_t)P * 16 + 255) / 256);   // pair blocks

    // ---- workspace layout ----
    char* w = (char*)d_ws;
    float* dis    = (float*)w;  w += (size_t)N * 4;
    int*   rowptr = (int*)w;    w += ((size_t)N + 1) * 4;
    int*   gbase  = (int*)w;    w += 513 * 4;
    int*   gcur   = (int*)w;    w += 512 * 4;
    int*   srcs   = (int*)w;    w += (size_t)E * 4;
    size_t off = ((size_t)(w - (char*)d_ws) + 255) & ~(size_t)255;

    size_t featB = (size_t)N * HID * 2;     // bf16 feature buffer bytes
    unsigned short* bufA = (unsigned short*)((char*)d_ws + off);
    unsigned short* bufB = bufA + (size_t)N * HID;
    size_t need = off + 2 * featB;

    bool useNew = (N <= 131072) && (NBk <= 512) && (ws_size >= need) &&
                  ((size_t)E <= 20 * (size_t)N) &&
                  ((size_t)NBk * CAP * 4 <= 2 * featB);

    if (useNew) {
        unsigned* pbuf = (unsigned*)bufA;   // partition buffer aliases bufA/bufB (dead until GEMM1)

        // ---- CSR build (fixed-capacity buckets; no pre-count pass) ----
        k_initcur<<<2, 256, 0, stream>>>(gcur);
        k_partB<<<pa, 256, 0, stream>>>(erow, ecol, gcur, pbuf, E);
        k_scanB<<<1, 512, 0, stream>>>(gcur, gbase, NBk, E);
        k_passC<<<NBk, 256, 0, stream>>>(pbuf, gcur, gbase, rowptr, srcs, dis, N, E);

        // ---- layer 1 ----
        k_gemm<128, float, unsigned short><<<gb, 256, 0, stream>>>(x, W1, nullptr, dis, bufA, nullptr, N);
        k_gather<<<hb, 256, 0, stream>>>(bufA, rowptr, srcs, dis, b1, bufB, N, 1);
        // ---- layer 2 ----
        k_gemm<64, unsigned short, unsigned short><<<gb, 256, 0, stream>>>(bufB, W2, nullptr, dis, bufA, nullptr, N);
        k_gather<<<hb, 256, 0, stream>>>(bufA, rowptr, srcs, dis, b2, bufB, N, 0);
        // ---- fused link-pred projections: A->bufA, B->bufB (in-place safe) ----
        k_gemm2<unsigned short><<<gb, 256, 0, stream>>>(bufB, lpW1, lpb1, bufA, bufB, N);

        k_pair<<<pb, 256, 0, stream>>>(bufA, bufB, ep, lpW2, lpb2, out, P);
    } else {
        // ---- fallback: fp32 atomic scatter path ----
        size_t off_fb = (((size_t)N + (size_t)N + 1) * 4 + 255) & ~(size_t)255;
        float* fA = (float*)((char*)d_ws + off_fb);
        float* fB = fA + (size_t)N * HID;
        if (ws_size < off_fb + 2 * (size_t)N * HID * 4) return;
        const int nb = (N + 255) / 256;
        const int eb = (E + 255) / 256;
        const int sb = (int)(((size_t)E * 16 + 255) / 256);
        k_initf<<<nb, 256, 0, stream>>>(dis, 1.0f, N);
        k_count<<<eb, 256, 0, stream>>>(ecol, dis, E);
        k_rsqrt<<<nb, 256, 0, stream>>>(dis, N);
        k_gemm<128, float, float><<<gb, 256, 0, stream>>>(x, W1, nullptr, dis, fA, fB, N);
        k_scatter<<<sb, 256, 0, stream>>>(fA, erow, ecol, fB, E);
        k_finish<<<hb, 256, 0, stream>>>(fB, dis, b1, fB, N, 1);
        k_gemm<64, float, float><<<gb, 256, 0, stream>>>(fB, W2, nullptr, dis, fA, fB, N);
        k_scatter<<<sb, 256, 0, stream>>>(fA, erow, ecol, fB, E);
        k_finish<<<hb, 256, 0, stream>>>(fB, dis, b2, fB, N, 0);
        // bf16 A/B carved inside fA (g2 region, dead after scatter)
        unsigned short* bA = (unsigned short*)fA;
        unsigned short* bB = bA + (size_t)N * HID;
        k_gemm2<float><<<gb, 256, 0, stream>>>(fB, lpW1, lpb1, bA, bB, N);
        k_pair<<<pb, 256, 0, stream>>>(bA, bB, ep, lpW2, lpb2, out, P);
    }
}